// Round 5
// baseline (403.154 us; speedup 1.0000x reference)
//
#include <hip/hip_runtime.h>
#include <math.h>

typedef unsigned long long u64;
typedef float  f32x4 __attribute__((ext_vector_type(4)));
typedef int    i32x4 __attribute__((ext_vector_type(4)));

#define T_LEN   4096
#define VOCAB   50257
#define TOP_M   4
#define WEIGHT  0.5f
#define HASH_B  1315423911ull

#define CHAIN_BLOCKS  32
#define CHAIN_THREADS 128

#define COPY_BLOCKS   2048
#define COPY_THREADS  256
#define COPY_BATCH    8      // float4s per thread per chunk iteration

// ---------------- Kernel 1: per-slot chains, everything staged in LDS ----------------
__global__ void __launch_bounds__(CHAIN_THREADS) chain_kernel(const int* __restrict__ ids,
                                                              int* __restrict__ idxs,
                                                              float* __restrict__ vals) {
    __shared__ int sids[T_LEN];
    __shared__ int s[T_LEN];
    {
        i32x4* dst4 = (i32x4*)sids;
        const i32x4* g4 = (const i32x4*)ids;
        for (int i = threadIdx.x; i < T_LEN / 4; i += CHAIN_THREADS) dst4[i] = g4[i];
    }
    __syncthreads();
    const u64 B1 = HASH_B;
    const u64 B2 = B1 * B1;
    const u64 B3 = B2 * B1;
    for (int i = threadIdx.x; i < T_LEN; i += CHAIN_THREADS) {
        if (i < 3) { s[i] = -1; continue; }
        u64 fp = (u64)(unsigned)(sids[i - 3] + 1) * B3
               + (u64)(unsigned)(sids[i - 2] + 1) * B2
               + (u64)(unsigned)(sids[i - 1] + 1) * B1
               + (u64)(unsigned)(sids[i]     + 1);
        s[i] = (int)(fp & 0xFFFFull);
    }
    __syncthreads();

    int t = blockIdx.x * CHAIN_THREADS + threadIdx.x;
    if (t < 3) {
        *(i32x4*)&idxs[t * 4]  = (i32x4){0, 0, 0, 0};
        *(f32x4*)&vals[t * 4]  = (f32x4){0.f, 0.f, 0.f, 0.f};
        return;
    }
    const int mys = s[t];

    u64 key = 0ull;
    int tk[TOP_M] = {0, 0, 0, 0};
    int cs[TOP_M] = {0, 0, 0, 0};
    bool dead = false;

    const i32x4* s4 = (const i32x4*)s;
    for (int qb = 0; qb < T_LEN / 4; qb += 8) {
        i32x4 v[8];
        #pragma unroll
        for (int u = 0; u < 8; ++u) v[u] = s4[qb + u];
        bool any = false;
        #pragma unroll
        for (int u = 0; u < 8; ++u)
            any |= (v[u].x == mys) | (v[u].y == mys) | (v[u].z == mys) | (v[u].w == mys);
        if (!any) continue;

        #pragma unroll
        for (int u = 0; u < 8; ++u) {
            #pragma unroll
            for (int j = 0; j < 4; ++j) {
                int sv = (j == 0) ? v[u].x : (j == 1) ? v[u].y : (j == 2) ? v[u].z : v[u].w;
                if (sv != mys) continue;
                int tp = (qb + u) * 4 + j;
                if (tp < t) { dead = true; continue; }
                if (dead) continue;

                u64 wk = (u64)(unsigned)(sids[tp - 3] + 1) * B3
                       + (u64)(unsigned)(sids[tp - 2] + 1) * B2
                       + (u64)(unsigned)(sids[tp - 1] + 1) * B1
                       + (u64)(unsigned)(sids[tp]     + 1) + 1ull;
                bool key_match = (key == wk);

                int tot = 0;
                #pragma unroll
                for (int m = 0; m < TOP_M; ++m) tot += (tk[m] > 0) ? cs[m] : 0;
                bool emit = key_match && (tot > 0);
                float denom = fmaxf((float)tot, 1.0f);

                int   oi[TOP_M];
                float ov[TOP_M];
                #pragma unroll
                for (int m = 0; m < TOP_M; ++m) {
                    bool ok = emit && (tk[m] > 0) && (cs[m] > 0);
                    float p = fmaxf(1e-9f, (float)cs[m] / denom);
                    ov[m] = ok ? (logf(p) * WEIGHT) : 0.0f;
                    oi[m] = ok ? (tk[m] - 1) : 0;
                }
                *(i32x4*)&idxs[tp * 4] = (i32x4){oi[0], oi[1], oi[2], oi[3]};
                *(f32x4*)&vals[tp * 4] = (f32x4){ov[0], ov[1], ov[2], ov[3]};

                if (tp < T_LEN - 1) {
                    if (!key_match) {
                        #pragma unroll
                        for (int m = 0; m < TOP_M; ++m) { tk[m] = 0; cs[m] = 0; }
                    }
                    key = wk;
                    int ntp1 = sids[tp + 1] + 1;

                    int ins = -1;
                    #pragma unroll
                    for (int m = 0; m < TOP_M; ++m) if (ins < 0 && tk[m] == ntp1) ins = m;
                    bool matched = (ins >= 0);
                    if (ins < 0) {
                        #pragma unroll
                        for (int m = 0; m < TOP_M; ++m) if (ins < 0 && tk[m] == 0) ins = m;
                    }
                    if (ins < 0) {
                        int best = cs[0]; ins = 0;
                        #pragma unroll
                        for (int m = 1; m < TOP_M; ++m) if (cs[m] < best) { best = cs[m]; ins = m; }
                    }
                    int cur = 0;
                    #pragma unroll
                    for (int m = 0; m < TOP_M; ++m) if (m == ins) cur = cs[m];
                    int new_cnt = matched ? min(65535, cur + 1) : 1;
                    #pragma unroll
                    for (int m = 0; m < TOP_M; ++m) if (m == ins) { tk[m] = ntp1; cs[m] = new_cnt; }
                }
            }
        }
        if (dead) break;
    }
}

// ---------------- Kernel 2: chunked grid-stride copy, 8 nt-float4 in flight/thread ----------------
// Each chunk = COPY_THREADS*COPY_BATCH float4s handled by one block iteration;
// within a chunk, access u is src[chunk + u*COPY_THREADS + tid]: fully coalesced,
// 8 independent loads issued before any store (vmcnt pipelining).
__global__ void __launch_bounds__(COPY_THREADS) copy_kernel(const f32x4* __restrict__ src,
                                                            f32x4* __restrict__ dst,
                                                            size_t n4) {
    const size_t chunk_sz = (size_t)COPY_THREADS * COPY_BATCH;
    const size_t nchunks_full = n4 / chunk_sz;
    size_t tid = threadIdx.x;

    for (size_t c = blockIdx.x; c < nchunks_full; c += gridDim.x) {
        size_t base = c * chunk_sz + tid;
        f32x4 v[COPY_BATCH];
        #pragma unroll
        for (int u = 0; u < COPY_BATCH; ++u)
            v[u] = __builtin_nontemporal_load(&src[base + (size_t)u * COPY_THREADS]);
        #pragma unroll
        for (int u = 0; u < COPY_BATCH; ++u)
            __builtin_nontemporal_store(v[u], &dst[base + (size_t)u * COPY_THREADS]);
    }
    // remainder float4s (n4 % chunk_sz), one float4 per thread
    size_t rem_start = nchunks_full * chunk_sz;
    for (size_t k = rem_start + blockIdx.x * (size_t)COPY_THREADS + tid; k < n4;
         k += (size_t)gridDim.x * COPY_THREADS) {
        f32x4 v = __builtin_nontemporal_load(&src[k]);
        __builtin_nontemporal_store(v, &dst[k]);
    }
}

// scalar tail (out_size % 4), launched only if needed
__global__ void copy_tail_kernel(const float* __restrict__ src, float* __restrict__ dst,
                                 size_t start, size_t n_total) {
    size_t k = start + threadIdx.x;
    if (k < n_total) dst[k] = src[k];
}

// ---------------- Kernel 3: sparse scatter-add of deltas ----------------
__global__ void scatter_kernel(const int* __restrict__ idxs,
                               const float* __restrict__ vals,
                               float* __restrict__ out) {
    int i = blockIdx.x * blockDim.x + threadIdx.x;
    if (i >= T_LEN * TOP_M) return;
    float v = vals[i];
    if (v != 0.0f) {
        int t = i / TOP_M;
        atomicAdd(out + (size_t)t * VOCAB + idxs[i], v);
    }
}

extern "C" void kernel_launch(void* const* d_in, const int* in_sizes, int n_in,
                              void* d_out, int out_size, void* d_ws, size_t ws_size,
                              hipStream_t stream) {
    const float* logits = (const float*)d_in[0];
    const int*   ids    = (const int*)d_in[1];
    float*       out    = (float*)d_out;

    char* ws = (char*)d_ws;
    int*   idxs = (int*)(ws);              // 16384*4 = 64 KB
    float* vals = (float*)(ws + 65536);    // 64 KB

    chain_kernel<<<CHAIN_BLOCKS, CHAIN_THREADS, 0, stream>>>(ids, idxs, vals);

    size_t n_total = (size_t)out_size;
    size_t n4 = n_total / 4;
    copy_kernel<<<COPY_BLOCKS, COPY_THREADS, 0, stream>>>((const f32x4*)logits, (f32x4*)out, n4);
    if (n_total - n4 * 4)
        copy_tail_kernel<<<1, 64, 0, stream>>>(logits, out, n4 * 4, n_total);

    scatter_kernel<<<(T_LEN * TOP_M + 255) / 256, 256, 0, stream>>>(idxs, vals, out);
}

// Round 6
// 383.314 us; speedup vs baseline: 1.0518x; 1.0518x over previous
//
#include <hip/hip_runtime.h>
#include <math.h>

typedef unsigned long long u64;
typedef float  f32x4 __attribute__((ext_vector_type(4)));
typedef int    i32x4 __attribute__((ext_vector_type(4)));

#define T_LEN   4096
#define VOCAB   50257
#define TOP_M   4
#define WEIGHT  0.5f
#define HASH_B  1315423911ull

#define CHAIN_BLOCKS  32
#define CHAIN_THREADS 128

// ---------------- Kernel 1: per-slot chains, everything staged in LDS ----------------
__global__ void __launch_bounds__(CHAIN_THREADS) chain_kernel(const int* __restrict__ ids,
                                                              int* __restrict__ idxs,
                                                              float* __restrict__ vals) {
    __shared__ int sids[T_LEN];
    __shared__ int s[T_LEN];
    {
        i32x4* dst4 = (i32x4*)sids;
        const i32x4* g4 = (const i32x4*)ids;
        for (int i = threadIdx.x; i < T_LEN / 4; i += CHAIN_THREADS) dst4[i] = g4[i];
    }
    __syncthreads();
    const u64 B1 = HASH_B;
    const u64 B2 = B1 * B1;
    const u64 B3 = B2 * B1;
    for (int i = threadIdx.x; i < T_LEN; i += CHAIN_THREADS) {
        if (i < 3) { s[i] = -1; continue; }
        u64 fp = (u64)(unsigned)(sids[i - 3] + 1) * B3
               + (u64)(unsigned)(sids[i - 2] + 1) * B2
               + (u64)(unsigned)(sids[i - 1] + 1) * B1
               + (u64)(unsigned)(sids[i]     + 1);
        s[i] = (int)(fp & 0xFFFFull);
    }
    __syncthreads();

    int t = blockIdx.x * CHAIN_THREADS + threadIdx.x;
    if (t < 3) {
        *(i32x4*)&idxs[t * 4]  = (i32x4){0, 0, 0, 0};
        *(f32x4*)&vals[t * 4]  = (f32x4){0.f, 0.f, 0.f, 0.f};
        return;
    }
    const int mys = s[t];

    u64 key = 0ull;
    int tk[TOP_M] = {0, 0, 0, 0};
    int cs[TOP_M] = {0, 0, 0, 0};
    bool dead = false;

    const i32x4* s4 = (const i32x4*)s;
    for (int qb = 0; qb < T_LEN / 4; qb += 8) {
        i32x4 v[8];
        #pragma unroll
        for (int u = 0; u < 8; ++u) v[u] = s4[qb + u];
        bool any = false;
        #pragma unroll
        for (int u = 0; u < 8; ++u)
            any |= (v[u].x == mys) | (v[u].y == mys) | (v[u].z == mys) | (v[u].w == mys);
        if (!any) continue;

        #pragma unroll
        for (int u = 0; u < 8; ++u) {
            #pragma unroll
            for (int j = 0; j < 4; ++j) {
                int sv = (j == 0) ? v[u].x : (j == 1) ? v[u].y : (j == 2) ? v[u].z : v[u].w;
                if (sv != mys) continue;
                int tp = (qb + u) * 4 + j;
                if (tp < t) { dead = true; continue; }
                if (dead) continue;

                u64 wk = (u64)(unsigned)(sids[tp - 3] + 1) * B3
                       + (u64)(unsigned)(sids[tp - 2] + 1) * B2
                       + (u64)(unsigned)(sids[tp - 1] + 1) * B1
                       + (u64)(unsigned)(sids[tp]     + 1) + 1ull;
                bool key_match = (key == wk);

                int tot = 0;
                #pragma unroll
                for (int m = 0; m < TOP_M; ++m) tot += (tk[m] > 0) ? cs[m] : 0;
                bool emit = key_match && (tot > 0);
                float denom = fmaxf((float)tot, 1.0f);

                int   oi[TOP_M];
                float ov[TOP_M];
                #pragma unroll
                for (int m = 0; m < TOP_M; ++m) {
                    bool ok = emit && (tk[m] > 0) && (cs[m] > 0);
                    float p = fmaxf(1e-9f, (float)cs[m] / denom);
                    ov[m] = ok ? (logf(p) * WEIGHT) : 0.0f;
                    oi[m] = ok ? (tk[m] - 1) : 0;
                }
                *(i32x4*)&idxs[tp * 4] = (i32x4){oi[0], oi[1], oi[2], oi[3]};
                *(f32x4*)&vals[tp * 4] = (f32x4){ov[0], ov[1], ov[2], ov[3]};

                if (tp < T_LEN - 1) {
                    if (!key_match) {
                        #pragma unroll
                        for (int m = 0; m < TOP_M; ++m) { tk[m] = 0; cs[m] = 0; }
                    }
                    key = wk;
                    int ntp1 = sids[tp + 1] + 1;

                    int ins = -1;
                    #pragma unroll
                    for (int m = 0; m < TOP_M; ++m) if (ins < 0 && tk[m] == ntp1) ins = m;
                    bool matched = (ins >= 0);
                    if (ins < 0) {
                        #pragma unroll
                        for (int m = 0; m < TOP_M; ++m) if (ins < 0 && tk[m] == 0) ins = m;
                    }
                    if (ins < 0) {
                        int best = cs[0]; ins = 0;
                        #pragma unroll
                        for (int m = 1; m < TOP_M; ++m) if (cs[m] < best) { best = cs[m]; ins = m; }
                    }
                    int cur = 0;
                    #pragma unroll
                    for (int m = 0; m < TOP_M; ++m) if (m == ins) cur = cs[m];
                    int new_cnt = matched ? min(65535, cur + 1) : 1;
                    #pragma unroll
                    for (int m = 0; m < TOP_M; ++m) if (m == ins) { tk[m] = ntp1; cs[m] = new_cnt; }
                }
            }
        }
        if (dead) break;
    }
}

// ---------------- Kernel 2: dense copy, flat one float4/thread, PLAIN loads/stores ----------------
__global__ void copy_kernel(const f32x4* __restrict__ src, f32x4* __restrict__ dst,
                            size_t n4) {
    size_t k = (size_t)blockIdx.x * blockDim.x + threadIdx.x;
    if (k < n4) dst[k] = src[k];
}

// scalar tail (out_size % 4), launched only if needed
__global__ void copy_tail_kernel(const float* __restrict__ src, float* __restrict__ dst,
                                 size_t start, size_t n_total) {
    size_t k = start + threadIdx.x;
    if (k < n_total) dst[k] = src[k];
}

// ---------------- Kernel 3: sparse scatter-add of deltas ----------------
__global__ void scatter_kernel(const int* __restrict__ idxs,
                               const float* __restrict__ vals,
                               float* __restrict__ out) {
    int i = blockIdx.x * blockDim.x + threadIdx.x;
    if (i >= T_LEN * TOP_M) return;
    float v = vals[i];
    if (v != 0.0f) {
        int t = i / TOP_M;
        atomicAdd(out + (size_t)t * VOCAB + idxs[i], v);
    }
}

extern "C" void kernel_launch(void* const* d_in, const int* in_sizes, int n_in,
                              void* d_out, int out_size, void* d_ws, size_t ws_size,
                              hipStream_t stream) {
    const float* logits = (const float*)d_in[0];
    const int*   ids    = (const int*)d_in[1];
    float*       out    = (float*)d_out;

    char* ws = (char*)d_ws;
    int*   idxs = (int*)(ws);              // 16384*4 = 64 KB
    float* vals = (float*)(ws + 65536);    // 64 KB

    chain_kernel<<<CHAIN_BLOCKS, CHAIN_THREADS, 0, stream>>>(ids, idxs, vals);

    size_t n_total = (size_t)out_size;
    size_t n4 = n_total / 4;
    size_t nblk = (n4 + 255) / 256;
    copy_kernel<<<(uint32_t)nblk, 256, 0, stream>>>((const f32x4*)logits, (f32x4*)out, n4);
    if (n_total - n4 * 4)
        copy_tail_kernel<<<1, 64, 0, stream>>>(logits, out, n4 * 4, n_total);

    scatter_kernel<<<(T_LEN * TOP_M + 255) / 256, 256, 0, stream>>>(idxs, vals, out);
}